// Round 1
// baseline (194.668 us; speedup 1.0000x reference)
//
#include <hip/hip_runtime.h>

// LSTMClassifier: B=1024, T=1024, H=16, C=6
// One wave per batch element. 64 lanes = 64 gates, interleaved so that the
// 4 gates (i,f,g,o) of hidden unit j live in quad j (lanes 4j..4j+3).
// h is wave-uniform -> broadcast via v_readlane into SGPR FMA operands.
// Cross-gate combine via DPP quad_perm (no LDS anywhere).

#define T_LEN 1024
#define BATCH 1024

__device__ __forceinline__ float rlane(float v, int lane) {
    return __int_as_float(__builtin_amdgcn_readlane(__float_as_int(v), lane));
}

template<int N>
__device__ __forceinline__ float quad_bcast(float v) {
    // quad_perm ctrl replicating lane N of each quad: N | N<<2 | N<<4 | N<<6
    constexpr int ctrl = N * 0x55;
    return __int_as_float(
        __builtin_amdgcn_mov_dpp(__float_as_int(v), ctrl, 0xf, 0xf, true));
}

__device__ __forceinline__ float fast_exp2(float x) {
#if __has_builtin(__builtin_amdgcn_exp2f)
    return __builtin_amdgcn_exp2f(x);
#else
    return exp2f(x);
#endif
}

__device__ __forceinline__ float fast_rcp(float x) {
#if __has_builtin(__builtin_amdgcn_rcpf)
    return __builtin_amdgcn_rcpf(x);
#else
    return 1.0f / x;
#endif
}

__launch_bounds__(256)
__global__ void lstm_cls_kernel(const float* __restrict__ x,
                                const float* __restrict__ W_ih,
                                const float* __restrict__ W_hh,
                                const float* __restrict__ b_ih,
                                const float* __restrict__ b_hh,
                                const float* __restrict__ W_fc,
                                const float* __restrict__ b_fc,
                                float* __restrict__ out) {
    const int tid  = threadIdx.x;
    const int wave = tid >> 6;
    const int lane = tid & 63;
    const int b    = blockIdx.x * 4 + wave;   // one batch per wave
    const int j    = lane >> 2;               // hidden index 0..15
    const int q    = lane & 3;                // 0=i, 1=f, 2=g, 3=o
    const int row  = q * 16 + j;              // row in [4H] (PyTorch order)

    // Per-lane recurrent weights: W_hh[row, 0..15]
    const float4* wr = (const float4*)(W_hh + row * 16);
    const float4 w0 = wr[0], w1 = wr[1], w2 = wr[2], w3 = wr[3];

    const float wih  = W_ih[row];
    const float bias = b_ih[row] + b_hh[row];

    const float LOG2E = 1.44269504088896340736f;
    // Unified activation: r = rcp(1 + exp2(kk*a)); act = Aa*r + Bb
    // sigmoid: kk=-log2e, Aa=1, Bb=0 ; tanh: kk=-2log2e, Aa=2, Bb=-1
    const float kk = (q == 2) ? (-2.0f * LOG2E) : (-LOG2E);
    const float Aa = (q == 2) ? 2.0f : 1.0f;
    const float Bb = (q == 2) ? -1.0f : 0.0f;

    float h = 0.0f;
    float c = 0.0f;

    // x stream: 256 float4 chunks per batch, 2-chunk prefetch depth
    const float4* xv = (const float4*)(x + (size_t)b * T_LEN);
    float4 bufA = xv[0];
    float4 bufB = xv[1];

    for (int ch = 0; ch < T_LEN / 4; ++ch) {
        const float4 cur = bufA;
        bufA = bufB;
        int nidx = ch + 2;
        if (nidx > T_LEN / 4 - 1) nidx = T_LEN / 4 - 1;
        bufB = xv[nidx];

        #pragma unroll
        for (int s = 0; s < 4; ++s) {
            const float xs = (s == 0) ? cur.x : (s == 1) ? cur.y
                           : (s == 2) ? cur.z : cur.w;

            // gate preactivation: xs*wih + bias + sum_k W_hh[row,k]*h_k
            float a0 = fmaf(xs, wih, bias);
            float a1 = 0.0f, a2 = 0.0f, a3 = 0.0f;
            a0 = fmaf(w0.x, rlane(h,  0), a0);
            a1 = fmaf(w0.y, rlane(h,  4), a1);
            a2 = fmaf(w0.z, rlane(h,  8), a2);
            a3 = fmaf(w0.w, rlane(h, 12), a3);
            a0 = fmaf(w1.x, rlane(h, 16), a0);
            a1 = fmaf(w1.y, rlane(h, 20), a1);
            a2 = fmaf(w1.z, rlane(h, 24), a2);
            a3 = fmaf(w1.w, rlane(h, 28), a3);
            a0 = fmaf(w2.x, rlane(h, 32), a0);
            a1 = fmaf(w2.y, rlane(h, 36), a1);
            a2 = fmaf(w2.z, rlane(h, 40), a2);
            a3 = fmaf(w2.w, rlane(h, 44), a3);
            a0 = fmaf(w3.x, rlane(h, 48), a0);
            a1 = fmaf(w3.y, rlane(h, 52), a1);
            a2 = fmaf(w3.z, rlane(h, 56), a2);
            a3 = fmaf(w3.w, rlane(h, 60), a3);
            const float a = (a0 + a1) + (a2 + a3);

            // per-lane activation (sigmoid or tanh, uniform code path)
            const float e   = fast_exp2(kk * a);
            const float r   = fast_rcp(1.0f + e);
            const float act = fmaf(Aa, r, Bb);

            // gather i,f,g,o within the quad (DPP)
            const float vi = quad_bcast<0>(act);
            const float vf = quad_bcast<1>(act);
            const float vg = quad_bcast<2>(act);
            const float vo = quad_bcast<3>(act);

            c = fmaf(vf, c, vi * vg);

            // tanh(c)
            const float e2 = fast_exp2(-2.0f * LOG2E * c);
            const float r2 = fast_rcp(1.0f + e2);
            const float tc = fmaf(2.0f, r2, -1.0f);

            h = vo * tc;
        }
    }

    // Epilogue: logits[b, cc] = b_fc[cc] + sum_k W_fc[cc,k] * h_k
    float hv[16];
    #pragma unroll
    for (int k = 0; k < 16; ++k) hv[k] = rlane(h, 4 * k);

    if (lane < 6) {
        const float* wf = W_fc + lane * 16;
        float acc = b_fc[lane];
        #pragma unroll
        for (int k = 0; k < 16; ++k) acc = fmaf(wf[k], hv[k], acc);
        out[b * 6 + lane] = acc;
    }
}

extern "C" void kernel_launch(void* const* d_in, const int* in_sizes, int n_in,
                              void* d_out, int out_size, void* d_ws, size_t ws_size,
                              hipStream_t stream) {
    const float* x    = (const float*)d_in[0];
    const float* W_ih = (const float*)d_in[1];
    const float* W_hh = (const float*)d_in[2];
    const float* b_ih = (const float*)d_in[3];
    const float* b_hh = (const float*)d_in[4];
    const float* W_fc = (const float*)d_in[5];
    const float* b_fc = (const float*)d_in[6];
    float* out = (float*)d_out;

    // 1024 batches, 1 wave each, 4 waves (256 threads) per block
    lstm_cls_kernel<<<BATCH / 4, 256, 0, stream>>>(x, W_ih, W_hh, b_ih, b_hh,
                                                   W_fc, b_fc, out);
}

// Round 2
// 171.027 us; speedup vs baseline: 1.1382x; 1.1382x over previous
//
#include <hip/hip_runtime.h>

// LSTMClassifier: B=1024, T=1024, H=16, C=6
// One wave per batch element (1024 waves = 1 per SIMD; max parallelism).
// Lane 4j+q owns gate q of hidden unit j. h broadcast via v_readlane -> SGPR
// FMA operands; cross-gate combine via DPP quad_perm. x preloaded into 16
// VGPRs per lane and broadcast per-step with v_readlane (no in-loop loads).

#define T_LEN 1024
#define BATCH 1024

__device__ __forceinline__ float rlane(float v, int l) {
    return __int_as_float(__builtin_amdgcn_readlane(__float_as_int(v), l));
}

template<int N>
__device__ __forceinline__ float quad_bcast(float v) {
    constexpr int ctrl = N * 0x55;  // replicate lane N of each quad
    return __int_as_float(
        __builtin_amdgcn_mov_dpp(__float_as_int(v), ctrl, 0xf, 0xf, true));
}

__device__ __forceinline__ float fexp2(float x) {
#if __has_builtin(__builtin_amdgcn_exp2f)
    return __builtin_amdgcn_exp2f(x);
#else
    return exp2f(x);
#endif
}

__device__ __forceinline__ float frcp(float x) {
#if __has_builtin(__builtin_amdgcn_rcpf)
    return __builtin_amdgcn_rcpf(x);
#else
    return 1.0f / x;
#endif
}

__launch_bounds__(256)
__global__ void lstm_cls_kernel(const float* __restrict__ x,
                                const float* __restrict__ W_ih,
                                const float* __restrict__ W_hh,
                                const float* __restrict__ b_ih,
                                const float* __restrict__ b_hh,
                                const float* __restrict__ W_fc,
                                const float* __restrict__ b_fc,
                                float* __restrict__ out) {
    const int tid  = threadIdx.x;
    const int wave = tid >> 6;
    const int lane = tid & 63;
    const int b    = blockIdx.x * 4 + wave;   // one batch per wave
    const int j    = lane >> 2;               // hidden unit 0..15
    const int q    = lane & 3;                // 0=i, 1=f, 2=g, 3=o
    const int row  = q * 16 + j;              // row in [4H] (PyTorch order)

    // Per-lane recurrent weights: W_hh[row, 0..15]
    const float4* wr = (const float4*)(W_hh + row * 16);
    const float4 w0 = wr[0], w1 = wr[1], w2 = wr[2], w3 = wr[3];

    const float wih  = W_ih[row];
    const float bias = b_ih[row] + b_hh[row];

    const float LOG2E = 1.44269504088896340736f;
    // r = 1/(1+exp2(kk*a)): sigmoid for q!=2; (tanh+1)/2 for q==2
    const float kk = (q == 2) ? (-2.0f * LOG2E) : (-LOG2E);

    // Preload the wave's x sequence: element 4*lane + 256*k + comp
    const float4* xv = (const float4*)(x + (size_t)b * T_LEN);
    const float4 xq0 = xv[lane];
    const float4 xq1 = xv[lane + 64];
    const float4 xq2 = xv[lane + 128];
    const float4 xq3 = xv[lane + 192];

    float h = 0.0f;
    float c = 0.0f;

    auto step = [&](float xs) {
        // gate preactivation: xs*wih + bias + sum_k W_hh[row,k]*h_k
        float a0 = fmaf(xs, wih, bias);
        float a1 = 0.0f, a2 = 0.0f, a3 = 0.0f;
        a0 = fmaf(w0.x, rlane(h,  0), a0);
        a1 = fmaf(w0.y, rlane(h,  4), a1);
        a2 = fmaf(w0.z, rlane(h,  8), a2);
        a3 = fmaf(w0.w, rlane(h, 12), a3);
        a0 = fmaf(w1.x, rlane(h, 16), a0);
        a1 = fmaf(w1.y, rlane(h, 20), a1);
        a2 = fmaf(w1.z, rlane(h, 24), a2);
        a3 = fmaf(w1.w, rlane(h, 28), a3);
        a0 = fmaf(w2.x, rlane(h, 32), a0);
        a1 = fmaf(w2.y, rlane(h, 36), a1);
        a2 = fmaf(w2.z, rlane(h, 40), a2);
        a3 = fmaf(w2.w, rlane(h, 44), a3);
        a0 = fmaf(w3.x, rlane(h, 48), a0);
        a1 = fmaf(w3.y, rlane(h, 52), a1);
        a2 = fmaf(w3.z, rlane(h, 56), a2);
        a3 = fmaf(w3.w, rlane(h, 60), a3);
        const float a = (a0 + a1) + (a2 + a3);

        // unified activation core (per lane): r
        const float r = frcp(1.0f + fexp2(kk * a));

        // quad gather: r0=i(sig) r1=f(sig) r2=(tanh g +1)/2 r3=o(sig)
        const float r0 = quad_bcast<0>(r);
        const float r1 = quad_bcast<1>(r);
        const float r2 = quad_bcast<2>(r);
        const float r3 = quad_bcast<3>(r);

        // i*g = r0*(2*r2-1) = 2*r0*r2 - r0
        const float t0 = r0 + r0;
        const float ig = fmaf(t0, r2, -r0);
        c = fmaf(r1, c, ig);

        // h = o*tanh(c) = 2*o*rt - o, rt = 1/(1+exp2(-2c*log2e))
        const float t3 = r3 + r3;   // issues in the exp latency shadow
        const float rt = frcp(1.0f + fexp2(-2.0f * LOG2E * c));
        h = fmaf(t3, rt, -r3);
    };

    #pragma unroll
    for (int k = 0; k < 4; ++k) {
        const float4 xk = (k == 0) ? xq0 : (k == 1) ? xq1
                        : (k == 2) ? xq2 : xq3;
        for (int r = 0; r < 64; ++r) {
            step(rlane(xk.x, r));
            step(rlane(xk.y, r));
            step(rlane(xk.z, r));
            step(rlane(xk.w, r));
        }
    }

    // Epilogue: logits[b, cc] = b_fc[cc] + sum_k W_fc[cc,k] * h_k
    float hv[16];
    #pragma unroll
    for (int k = 0; k < 16; ++k) hv[k] = rlane(h, 4 * k);

    if (lane < 6) {
        const float* wf = W_fc + lane * 16;
        float acc = b_fc[lane];
        #pragma unroll
        for (int k = 0; k < 16; ++k) acc = fmaf(wf[k], hv[k], acc);
        out[b * 6 + lane] = acc;
    }
}

extern "C" void kernel_launch(void* const* d_in, const int* in_sizes, int n_in,
                              void* d_out, int out_size, void* d_ws, size_t ws_size,
                              hipStream_t stream) {
    const float* x    = (const float*)d_in[0];
    const float* W_ih = (const float*)d_in[1];
    const float* W_hh = (const float*)d_in[2];
    const float* b_ih = (const float*)d_in[3];
    const float* b_hh = (const float*)d_in[4];
    const float* W_fc = (const float*)d_in[5];
    const float* b_fc = (const float*)d_in[6];
    float* out = (float*)d_out;

    lstm_cls_kernel<<<BATCH / 4, 256, 0, stream>>>(x, W_ih, W_hh, b_ih, b_hh,
                                                   W_fc, b_fc, out);
}